// Round 2
// baseline (5239.420 us; speedup 1.0000x reference)
//
#include <hip/hip_runtime.h>
#include <cstdint>
#include <cstddef>

// ---------------------------------------------------------------------------
// EGT layer, f32.  N nodes (DIM=96, H=32, HD=3), E edges.
// Atomic-free aggregation via CSR bucketing (count/scan/scatter/gather).
// ---------------------------------------------------------------------------

__device__ __forceinline__ float red32(float v) {
    #pragma unroll
    for (int m = 16; m >= 1; m >>= 1) v += __shfl_xor(v, m, 64);
    return v;
}

// ---------------- row LayerNorm over D=96 ----------------
__global__ __launch_bounds__(256) void ln96_kernel(
    const float* __restrict__ x, const float* __restrict__ g,
    const float* __restrict__ b, float* __restrict__ y, int M)
{
    int lane = threadIdx.x & 31;
    int grp  = threadIdx.x >> 5;
    int r = blockIdx.x * 8 + grp;
    if (r >= M) return;
    const float* xr = x + (size_t)r * 96;
    float a0 = xr[lane], a1 = xr[lane + 32], a2 = xr[lane + 64];
    float mu = red32(a0 + a1 + a2) * (1.f / 96.f);
    float d0 = a0 - mu, d1 = a1 - mu, d2 = a2 - mu;
    float var = red32(d0 * d0 + d1 * d1 + d2 * d2) * (1.f / 96.f);
    float rs = rsqrtf(var + 1e-5f);
    float* yr = y + (size_t)r * 96;
    yr[lane]      = d0 * rs * g[lane]      + b[lane];
    yr[lane + 32] = d1 * rs * g[lane + 32] + b[lane + 32];
    yr[lane + 64] = d2 * rs * g[lane + 64] + b[lane + 64];
}

// ---------------- generic small-N GEMM: C[M,*] = A[M,K] @ B[K,*] + bias -----
template<int RELU, int RES>
__global__ __launch_bounds__(192) void gemm_kernel(
    const float* __restrict__ A, int lda,
    const float* __restrict__ B, int ldb,
    const float* __restrict__ bias,
    const float* __restrict__ resid,
    const float* __restrict__ wptr,
    float* __restrict__ C, int ldc, int n0,
    int M, int K)
{
    __shared__ float sA[32 * 68];
    __shared__ float sB[32 * 48];
    const int tid = threadIdx.x;
    const int tx = tid % 12;
    const int ty = tid / 12;
    const int m0 = blockIdx.x * 64;
    const int nb = blockIdx.y * 48;
    float acc[4][4] = {};

    for (int kc = 0; kc < K; kc += 32) {
        for (int idx = tid; idx < 64 * 32; idx += 192) {
            int m = idx >> 5, k = idx & 31;
            int row = m0 + m;
            sA[k * 68 + m] = (row < M) ? A[(size_t)row * lda + kc + k] : 0.f;
        }
        for (int idx = tid; idx < 32 * 48; idx += 192) {
            int k = idx / 48, n = idx - k * 48;
            sB[idx] = B[(size_t)(kc + k) * ldb + nb + n];
        }
        __syncthreads();
        #pragma unroll
        for (int k = 0; k < 32; k++) {
            float4 av = *(const float4*)&sA[k * 68 + ty * 4];
            float4 bv = *(const float4*)&sB[k * 48 + tx * 4];
            float a4[4] = {av.x, av.y, av.z, av.w};
            float b4[4] = {bv.x, bv.y, bv.z, bv.w};
            #pragma unroll
            for (int i = 0; i < 4; i++)
                #pragma unroll
                for (int j = 0; j < 4; j++)
                    acc[i][j] += a4[i] * b4[j];
        }
        __syncthreads();
    }

    float scale = 1.f;
    if (RES) scale = wptr ? (1.f + wptr[0]) : 1.f;
    #pragma unroll
    for (int i = 0; i < 4; i++) {
        int row = m0 + ty * 4 + i;
        if (row >= M) continue;
        #pragma unroll
        for (int j = 0; j < 4; j++) {
            int col = nb + tx * 4 + j;
            float v = acc[i][j] + bias[col];
            if (RELU) v = fmaxf(v, 0.f);
            if (RES) v += scale * resid[(size_t)row * ldc + n0 + col];
            C[(size_t)row * ldc + n0 + col] = v;
        }
    }
}

// ---------------- CSR bucketing ----------------
__global__ __launch_bounds__(256) void count_kernel(
    const int* __restrict__ dst, int* __restrict__ cnt, int E)
{
    int i = blockIdx.x * 256 + threadIdx.x;
    if (i < E) atomicAdd(&cnt[dst[i]], 1);
}

__global__ __launch_bounds__(1024) void scan_kernel(
    const int* __restrict__ cnt, int* __restrict__ off, int* __restrict__ cur, int N)
{
    __shared__ int s[1024];
    const int tid = threadIdx.x;
    const int chunk = (N + 1023) >> 10;
    const int lo = tid * chunk;
    const int hi = min(lo + chunk, N);
    int sum = 0;
    for (int i = lo; i < hi; i++) sum += cnt[i];
    s[tid] = sum;
    __syncthreads();
    for (int d = 1; d < 1024; d <<= 1) {
        int v = (tid >= d) ? s[tid - d] : 0;
        __syncthreads();
        s[tid] += v;
        __syncthreads();
    }
    int base = (tid == 0) ? 0 : s[tid - 1];
    for (int i = lo; i < hi; i++) {
        off[i] = base; cur[i] = base;
        base += cnt[i];
    }
}

__global__ __launch_bounds__(256) void scatter_kernel(
    const int* __restrict__ dst, int* __restrict__ cur,
    int* __restrict__ eidx, int E)
{
    int i = blockIdx.x * 256 + threadIdx.x;
    if (i < E) {
        int p = atomicAdd(&cur[dst[i]], 1);
        eidx[p] = i;
    }
}

// ---------------- edge pass: one 32-lane group per edge ----------------
// ew=LN(edge), B=ew@Wb, ve=ew@We, score, ex=exp(score); streams {ex, ex*ve}
// to exve[E][32][2]; writes final e output row (score+edge + FFN).  NO atomics.
__global__ __launch_bounds__(256, 4) void edge_kernel(
    const float* __restrict__ edge, const float* __restrict__ qkv,
    const int* __restrict__ src, const int* __restrict__ dst,
    const float* __restrict__ We, const float* __restrict__ be,
    const float* __restrict__ Wb, const float* __restrict__ bb,
    const float* __restrict__ Wf0, const float* __restrict__ bf0,
    const float* __restrict__ Wf1, const float* __restrict__ bf1,
    const float* __restrict__ ge0, const float* __restrict__ be0,
    const float* __restrict__ ge1, const float* __restrict__ be1,
    float* __restrict__ exve, float* __restrict__ eout, int E)
{
    __shared__ float sWb[1024], sWe[1024], sWf0[2048], sWf1[2048];
    __shared__ float sbb[32], sbe[32], sbf0[64], sbf1[32];
    __shared__ float sge0[32], sbe0[32], sge1[32], sbe1[32];
    const int tid = threadIdx.x;
    for (int i = tid; i < 1024; i += 256) { sWb[i] = Wb[i]; sWe[i] = We[i]; }
    for (int i = tid; i < 2048; i += 256) { sWf0[i] = Wf0[i]; sWf1[i] = Wf1[i]; }
    if (tid < 32) {
        sbb[tid] = bb[tid]; sbe[tid] = be[tid]; sbf1[tid] = bf1[tid];
        sge0[tid] = ge0[tid]; sbe0[tid] = be0[tid];
        sge1[tid] = ge1[tid]; sbe1[tid] = be1[tid];
    }
    if (tid < 64) sbf0[tid] = bf0[tid];
    __syncthreads();

    const int lane = tid & 31;
    const int grp  = tid >> 5;
    const long long stride = (long long)gridDim.x * 8;

    for (long long e = (long long)blockIdx.x * 8 + grp; e < E; e += stride) {
        float ev = edge[e * 32 + lane];
        float mu = red32(ev) * (1.f / 32.f);
        float d  = ev - mu;
        float var = red32(d * d) * (1.f / 32.f);
        float rs = rsqrtf(var + 1e-5f);
        float ew = d * rs * sge0[lane] + sbe0[lane];
        float accB = sbb[lane], accVe = sbe[lane];
        #pragma unroll
        for (int i = 0; i < 32; i++) {
            float ewi = __shfl(ew, i, 32);
            accB  += ewi * sWb[i * 32 + lane];
            accVe += ewi * sWe[i * 32 + lane];
        }
        int sn = src[e], dn = dst[e];
        const float* qrow = qkv + (size_t)dn * 288;
        const float* krow = qkv + (size_t)sn * 288 + 96;
        float q0 = qrow[lane * 3], q1 = qrow[lane * 3 + 1], q2 = qrow[lane * 3 + 2];
        float k0 = krow[lane * 3], k1 = krow[lane * 3 + 1], k2 = krow[lane * 3 + 2];
        float score = (k0 * q0 + k1 * q1 + k2 * q2) * 0.5f + accB;
        float ex = __expf(score);
        float2 st; st.x = ex; st.y = ex * accVe;
        *(float2*)(exve + (size_t)e * 64 + lane * 2) = st;
        // e output: er + FFN(LN(er))
        float er = score + ev;
        float mu2 = red32(er) * (1.f / 32.f);
        float dd = er - mu2;
        float var2 = red32(dd * dd) * (1.f / 32.f);
        float rs2 = rsqrtf(var2 + 1e-5f);
        float en = dd * rs2 * sge1[lane] + sbe1[lane];
        float f0 = sbf0[lane], f1 = sbf0[lane + 32];
        #pragma unroll
        for (int i = 0; i < 32; i++) {
            float eni = __shfl(en, i, 32);
            f0 += eni * sWf0[i * 64 + lane];
            f1 += eni * sWf0[i * 64 + 32 + lane];
        }
        f0 = fmaxf(f0, 0.f);
        f1 = fmaxf(f1, 0.f);
        float acc = sbf1[lane] + er;
        #pragma unroll
        for (int j = 0; j < 32; j++) {
            float a = __shfl(f0, j, 32);
            float b = __shfl(f1, j, 32);
            acc += a * sWf1[j * 32 + lane] + b * sWf1[(32 + j) * 32 + lane];
        }
        eout[e * 32 + lane] = acc;
    }
}

// ---------------- gather: one wave per node, lanes = (half, head) ----------
// agg[n][h*4+c] = sum_e ex*{v0,v1,v2,ve} / sum_e ex   (normalized here)
__global__ __launch_bounds__(256) void gather_kernel(
    const float* __restrict__ exve, const float* __restrict__ qkv,
    const int* __restrict__ src, const int* __restrict__ eidx,
    const int* __restrict__ off, const int* __restrict__ cnt,
    float* __restrict__ agg, int N)
{
    const int wave = threadIdx.x >> 6;
    const int lane = threadIdx.x & 63;
    const int head = lane & 31;
    const int half = lane >> 5;
    int n = blockIdx.x * 4 + wave;
    if (n >= N) return;
    const int o = off[n], d = cnt[n];
    float a0 = 0.f, a1 = 0.f, a2 = 0.f, a3 = 0.f, den = 0.f;
    for (int i = half; i < d; i += 2) {
        int e = eidx[o + i];
        int sn = src[e];
        float2 p = *(const float2*)(exve + (size_t)e * 64 + head * 2);
        const float* vr = qkv + (size_t)sn * 288 + 192 + head * 3;
        a0 += p.x * vr[0];
        a1 += p.x * vr[1];
        a2 += p.x * vr[2];
        a3 += p.y;
        den += p.x;
    }
    a0 += __shfl_xor(a0, 32, 64);
    a1 += __shfl_xor(a1, 32, 64);
    a2 += __shfl_xor(a2, 32, 64);
    a3 += __shfl_xor(a3, 32, 64);
    den += __shfl_xor(den, 32, 64);
    if (half == 0) {
        float s = (d > 0) ? 1.f / den : 0.f;
        float* ap = agg + (size_t)n * 128 + head * 4;
        ap[0] = a0 * s; ap[1] = a1 * s; ap[2] = a2 * s; ap[3] = a3 * s;
    }
}

// ---------------------------------------------------------------------------
extern "C" void kernel_launch(void* const* d_in, const int* in_sizes, int n_in,
                              void* d_out, int out_size, void* d_ws, size_t ws_size,
                              hipStream_t stream)
{
    (void)n_in; (void)out_size; (void)ws_size;
    const float* feat = (const float*)d_in[0];
    const float* edge = (const float*)d_in[1];
    const float* Wq   = (const float*)d_in[2];
    const float* bq   = (const float*)d_in[3];
    const float* Wk   = (const float*)d_in[4];
    const float* bk   = (const float*)d_in[5];
    const float* Wv   = (const float*)d_in[6];
    const float* bv   = (const float*)d_in[7];
    const float* We   = (const float*)d_in[8];
    const float* be   = (const float*)d_in[9];
    const float* Wb   = (const float*)d_in[10];
    const float* bb   = (const float*)d_in[11];
    const float* Wvv  = (const float*)d_in[12];
    const float* bvv  = (const float*)d_in[13];
    const float* Wf0  = (const float*)d_in[14];
    const float* bf0  = (const float*)d_in[15];
    const float* Wf1  = (const float*)d_in[16];
    const float* bf1  = (const float*)d_in[17];
    const float* Wm0  = (const float*)d_in[18];
    const float* bm0  = (const float*)d_in[19];
    const float* Wm1  = (const float*)d_in[20];
    const float* bm1  = (const float*)d_in[21];
    const float* g_n0 = (const float*)d_in[22];
    const float* b_n0 = (const float*)d_in[23];
    const float* g_e0 = (const float*)d_in[24];
    const float* b_e0 = (const float*)d_in[25];
    const float* g_e1 = (const float*)d_in[26];
    const float* b_e1 = (const float*)d_in[27];
    const float* g_m  = (const float*)d_in[28];
    const float* b_m  = (const float*)d_in[29];
    const float* wsc  = (const float*)d_in[30];
    const int*   src  = (const int*)d_in[31];
    const int*   dst  = (const int*)d_in[32];

    const int N = in_sizes[0] / 96;
    const int E = in_sizes[1] / 32;

    float* ws    = (float*)d_ws;
    float* qkv   = ws;                                  // N*288
    float* agg   = qkv + (size_t)N * 288;               // N*128
    float* h0    = agg + (size_t)N * 128;               // N*96 (h0, later hn)
    float* hp    = h0 + (size_t)N * 96;                 // N*96
    float* exve  = hp + (size_t)N * 96;                 // E*64
    int*   eidx  = (int*)(exve + (size_t)E * 64);       // E
    int*   cnt   = eidx + E;                            // N
    int*   offv  = cnt + N;                             // N
    int*   cur   = offv + N;                            // N
    float* tbuf  = ws;                                  // N*192, reuses qkv late
    float* hout  = (float*)d_out;
    float* eoutp = (float*)d_out + (size_t)N * 96;

    hipMemsetAsync(cnt, 0, (size_t)N * sizeof(int), stream);

    const int mt = (N + 63) / 64;
    const int et = (E + 255) / 256;

    // CSR bucketing (independent of node-side work)
    count_kernel<<<et, 256, 0, stream>>>(dst, cnt, E);
    scan_kernel<<<1, 1024, 0, stream>>>(cnt, offv, cur, N);
    scatter_kernel<<<et, 256, 0, stream>>>(dst, cur, eidx, E);

    // node side: h0 = LN(feat); qkv = h0 @ [Wq|Wk|Wv]
    ln96_kernel<<<(N + 7) / 8, 256, 0, stream>>>(feat, g_n0, b_n0, h0, N);
    gemm_kernel<0,0><<<dim3(mt, 2), 192, 0, stream>>>(h0, 96, Wq, 96, bq, nullptr, nullptr, qkv, 288, 0,   N, 96);
    gemm_kernel<0,0><<<dim3(mt, 2), 192, 0, stream>>>(h0, 96, Wk, 96, bk, nullptr, nullptr, qkv, 288, 96,  N, 96);
    gemm_kernel<0,0><<<dim3(mt, 2), 192, 0, stream>>>(h0, 96, Wv, 96, bv, nullptr, nullptr, qkv, 288, 192, N, 96);

    // edge pass (streams exve, writes e output) — no atomics
    edge_kernel<<<4096, 256, 0, stream>>>(edge, qkv, src, dst,
                                          We, be, Wb, bb, Wf0, bf0, Wf1, bf1,
                                          g_e0, b_e0, g_e1, b_e1,
                                          exve, eoutp, E);

    // gather per node -> normalized agg[N,128]
    gather_kernel<<<(N + 3) / 4, 256, 0, stream>>>(exve, qkv, src, eidx, offv, cnt, agg, N);

    // h_pre = feat*(1+w) + agg @ Wvv + bvv
    gemm_kernel<0,1><<<dim3(mt, 2), 192, 0, stream>>>(agg, 128, Wvv, 96, bvv, feat, wsc, hp, 96, 0, N, 128);
    // hn = LN(h_pre)
    ln96_kernel<<<(N + 7) / 8, 256, 0, stream>>>(hp, g_m, b_m, h0, N);
    // t = relu(hn @ Wm0 + bm0)
    gemm_kernel<1,0><<<dim3(mt, 4), 192, 0, stream>>>(h0, 96, Wm0, 192, bm0, nullptr, nullptr, tbuf, 192, 0, N, 96);
    // h_out = h_pre + t @ Wm1 + bm1
    gemm_kernel<0,1><<<dim3(mt, 2), 192, 0, stream>>>(tbuf, 192, Wm1, 96, bm1, hp, nullptr, hout, 96, 0, N, 192);
}

// Round 3
// 2611.692 us; speedup vs baseline: 2.0061x; 2.0061x over previous
//
#include <hip/hip_runtime.h>
#include <cstdint>
#include <cstddef>

// ---------------------------------------------------------------------------
// EGT layer, f32.  N nodes (DIM=96, H=32, HD=3), E edges.
// Atomic-free aggregation via CSR bucketing; all row gathers staged through
// LDS as dense float4 loads (stride-12B per-lane gathers don't coalesce).
// ---------------------------------------------------------------------------

__device__ __forceinline__ float red32(float v) {
    #pragma unroll
    for (int m = 16; m >= 1; m >>= 1) v += __shfl_xor(v, m, 64);
    return v;
}

// ---------------- row LayerNorm over D=96 ----------------
__global__ __launch_bounds__(256) void ln96_kernel(
    const float* __restrict__ x, const float* __restrict__ g,
    const float* __restrict__ b, float* __restrict__ y, int M)
{
    int lane = threadIdx.x & 31;
    int grp  = threadIdx.x >> 5;
    int r = blockIdx.x * 8 + grp;
    if (r >= M) return;
    const float* xr = x + (size_t)r * 96;
    float a0 = xr[lane], a1 = xr[lane + 32], a2 = xr[lane + 64];
    float mu = red32(a0 + a1 + a2) * (1.f / 96.f);
    float d0 = a0 - mu, d1 = a1 - mu, d2 = a2 - mu;
    float var = red32(d0 * d0 + d1 * d1 + d2 * d2) * (1.f / 96.f);
    float rs = rsqrtf(var + 1e-5f);
    float* yr = y + (size_t)r * 96;
    yr[lane]      = d0 * rs * g[lane]      + b[lane];
    yr[lane + 32] = d1 * rs * g[lane + 32] + b[lane + 32];
    yr[lane + 64] = d2 * rs * g[lane + 64] + b[lane + 64];
}

// ---------------- generic small-N GEMM: C[M,*] = A[M,K] @ B[K,*] + bias -----
template<int RELU, int RES>
__global__ __launch_bounds__(192) void gemm_kernel(
    const float* __restrict__ A, int lda,
    const float* __restrict__ B, int ldb,
    const float* __restrict__ bias,
    const float* __restrict__ resid,
    const float* __restrict__ wptr,
    float* __restrict__ C, int ldc, int n0,
    int M, int K)
{
    __shared__ float sA[32 * 68];
    __shared__ float sB[32 * 48];
    const int tid = threadIdx.x;
    const int tx = tid % 12;
    const int ty = tid / 12;
    const int m0 = blockIdx.x * 64;
    const int nb = blockIdx.y * 48;
    float acc[4][4] = {};

    for (int kc = 0; kc < K; kc += 32) {
        for (int idx = tid; idx < 64 * 32; idx += 192) {
            int m = idx >> 5, k = idx & 31;
            int row = m0 + m;
            sA[k * 68 + m] = (row < M) ? A[(size_t)row * lda + kc + k] : 0.f;
        }
        for (int idx = tid; idx < 32 * 48; idx += 192) {
            int k = idx / 48, n = idx - k * 48;
            sB[idx] = B[(size_t)(kc + k) * ldb + nb + n];
        }
        __syncthreads();
        #pragma unroll
        for (int k = 0; k < 32; k++) {
            float4 av = *(const float4*)&sA[k * 68 + ty * 4];
            float4 bv = *(const float4*)&sB[k * 48 + tx * 4];
            float a4[4] = {av.x, av.y, av.z, av.w};
            float b4[4] = {bv.x, bv.y, bv.z, bv.w};
            #pragma unroll
            for (int i = 0; i < 4; i++)
                #pragma unroll
                for (int j = 0; j < 4; j++)
                    acc[i][j] += a4[i] * b4[j];
        }
        __syncthreads();
    }

    float scale = 1.f;
    if (RES) scale = wptr ? (1.f + wptr[0]) : 1.f;
    #pragma unroll
    for (int i = 0; i < 4; i++) {
        int row = m0 + ty * 4 + i;
        if (row >= M) continue;
        #pragma unroll
        for (int j = 0; j < 4; j++) {
            int col = nb + tx * 4 + j;
            float v = acc[i][j] + bias[col];
            if (RELU) v = fmaxf(v, 0.f);
            if (RES) v += scale * resid[(size_t)row * ldc + n0 + col];
            C[(size_t)row * ldc + n0 + col] = v;
        }
    }
}

// ---------------- CSR bucketing ----------------
__global__ __launch_bounds__(256) void count_kernel(
    const int* __restrict__ dst, int* __restrict__ cnt, int E)
{
    int i = blockIdx.x * 256 + threadIdx.x;
    if (i < E) atomicAdd(&cnt[dst[i]], 1);
}

__global__ __launch_bounds__(1024) void scan_kernel(
    const int* __restrict__ cnt, int* __restrict__ off, int* __restrict__ cur, int N)
{
    __shared__ int s[1024];
    const int tid = threadIdx.x;
    const int chunk = (N + 1023) >> 10;
    const int lo = tid * chunk;
    const int hi = min(lo + chunk, N);
    int sum = 0;
    for (int i = lo; i < hi; i++) sum += cnt[i];
    s[tid] = sum;
    __syncthreads();
    for (int d = 1; d < 1024; d <<= 1) {
        int v = (tid >= d) ? s[tid - d] : 0;
        __syncthreads();
        s[tid] += v;
        __syncthreads();
    }
    int base = (tid == 0) ? 0 : s[tid - 1];
    for (int i = lo; i < hi; i++) {
        off[i] = base; cur[i] = base;
        base += cnt[i];
    }
}

__global__ __launch_bounds__(256) void scatter_kernel(
    const int* __restrict__ dst, int* __restrict__ cur,
    int* __restrict__ eidx, int E)
{
    int i = blockIdx.x * 256 + threadIdx.x;
    if (i < E) {
        int p = atomicAdd(&cur[dst[i]], 1);
        eidx[p] = i;
    }
}

// ---------------- edge pass: one 32-lane group per edge ----------------
__global__ __launch_bounds__(256, 4) void edge_kernel(
    const float* __restrict__ edge, const float* __restrict__ qkv,
    const int* __restrict__ src, const int* __restrict__ dst,
    const float* __restrict__ We, const float* __restrict__ be,
    const float* __restrict__ Wb, const float* __restrict__ bb,
    const float* __restrict__ Wf0, const float* __restrict__ bf0,
    const float* __restrict__ Wf1, const float* __restrict__ bf1,
    const float* __restrict__ ge0, const float* __restrict__ be0,
    const float* __restrict__ ge1, const float* __restrict__ be1,
    float* __restrict__ exve, float* __restrict__ eout, int E)
{
    __shared__ float sWb[1024], sWe[1024], sWf0[2048], sWf1[2048];
    __shared__ float sQK[8][2][96];       // [group][q/k][row], float4-staged
    __shared__ float sbb[32], sbe[32], sbf0[64], sbf1[32];
    __shared__ float sge0[32], sbe0[32], sge1[32], sbe1[32];
    const int tid = threadIdx.x;
    for (int i = tid; i < 1024; i += 256) { sWb[i] = Wb[i]; sWe[i] = We[i]; }
    for (int i = tid; i < 2048; i += 256) { sWf0[i] = Wf0[i]; sWf1[i] = Wf1[i]; }
    if (tid < 32) {
        sbb[tid] = bb[tid]; sbe[tid] = be[tid]; sbf1[tid] = bf1[tid];
        sge0[tid] = ge0[tid]; sbe0[tid] = be0[tid];
        sge1[tid] = ge1[tid]; sbe1[tid] = be1[tid];
    }
    if (tid < 64) sbf0[tid] = bf0[tid];
    __syncthreads();

    const int lane = tid & 31;
    const int grp  = tid >> 5;
    const long long stride = (long long)gridDim.x * 8;

    for (long long e = (long long)blockIdx.x * 8 + grp; e < E; e += stride) {
        float ev = edge[e * 32 + lane];
        float mu = red32(ev) * (1.f / 32.f);
        float d  = ev - mu;
        float var = red32(d * d) * (1.f / 32.f);
        float rs = rsqrtf(var + 1e-5f);
        float ew = d * rs * sge0[lane] + sbe0[lane];

        int sn = src[e], dn = dst[e];
        // stage q[dst] and k[src] rows densely (float4, coalesced)
        if (lane < 24) {
            float4 qv = *(const float4*)(qkv + (size_t)dn * 288 + lane * 4);
            float4 kv = *(const float4*)(qkv + (size_t)sn * 288 + 96 + lane * 4);
            *(float4*)&sQK[grp][0][lane * 4] = qv;
            *(float4*)&sQK[grp][1][lane * 4] = kv;
        }
        __builtin_amdgcn_wave_barrier();   // same-wave LDS order; no s_barrier

        float accB = sbb[lane], accVe = sbe[lane];
        #pragma unroll
        for (int i = 0; i < 32; i++) {
            float ewi = __shfl(ew, i, 32);
            accB  += ewi * sWb[i * 32 + lane];
            accVe += ewi * sWe[i * 32 + lane];
        }
        float q0 = sQK[grp][0][lane * 3], q1 = sQK[grp][0][lane * 3 + 1], q2 = sQK[grp][0][lane * 3 + 2];
        float k0 = sQK[grp][1][lane * 3], k1 = sQK[grp][1][lane * 3 + 1], k2 = sQK[grp][1][lane * 3 + 2];
        float score = (k0 * q0 + k1 * q1 + k2 * q2) * 0.5f + accB;
        __builtin_amdgcn_wave_barrier();
        float ex = __expf(score);
        float2 st; st.x = ex; st.y = ex * accVe;
        *(float2*)(exve + (size_t)e * 64 + lane * 2) = st;
        // e output: er + FFN(LN(er))
        float er = score + ev;
        float mu2 = red32(er) * (1.f / 32.f);
        float dd = er - mu2;
        float var2 = red32(dd * dd) * (1.f / 32.f);
        float rs2 = rsqrtf(var2 + 1e-5f);
        float en = dd * rs2 * sge1[lane] + sbe1[lane];
        float f0 = sbf0[lane], f1 = sbf0[lane + 32];
        #pragma unroll
        for (int i = 0; i < 32; i++) {
            float eni = __shfl(en, i, 32);
            f0 += eni * sWf0[i * 64 + lane];
            f1 += eni * sWf0[i * 64 + 32 + lane];
        }
        f0 = fmaxf(f0, 0.f);
        f1 = fmaxf(f1, 0.f);
        float acc = sbf1[lane] + er;
        #pragma unroll
        for (int j = 0; j < 32; j++) {
            float a = __shfl(f0, j, 32);
            float b = __shfl(f1, j, 32);
            acc += a * sWf1[j * 32 + lane] + b * sWf1[(32 + j) * 32 + lane];
        }
        eout[e * 32 + lane] = acc;
    }
}

// ---------------- gather: one wave per node, halves process alt. edges -----
__global__ __launch_bounds__(256) void gather_kernel(
    const float* __restrict__ exve, const float* __restrict__ qkv,
    const int* __restrict__ src, const int* __restrict__ eidx,
    const int* __restrict__ off, const int* __restrict__ cnt,
    float* __restrict__ agg, int N)
{
    __shared__ float sV[4][2][96];    // [wave][half][v row]
    __shared__ float sE[4][2][64];    // [wave][half][exve row]
    const int wave = threadIdx.x >> 6;
    const int lane = threadIdx.x & 63;
    const int head = lane & 31;
    const int half = lane >> 5;
    int n = blockIdx.x * 4 + wave;
    if (n >= N) return;
    const int o = off[n], d = cnt[n];
    float a0 = 0.f, a1 = 0.f, a2 = 0.f, a3 = 0.f, den = 0.f;
    for (int i = half; i < d; i += 2) {
        int e = eidx[o + i];
        int sn = src[e];
        const float* vr = qkv + (size_t)sn * 288 + 192;
        const float* er = exve + (size_t)e * 64;
        if (head < 24) {
            *(float4*)&sV[wave][half][head * 4] = *(const float4*)(vr + head * 4);
        } else {
            int j = head - 24;   // 0..7 -> 2 float4 each = 256B
            *(float4*)&sE[wave][half][j * 8]     = *(const float4*)(er + j * 8);
            *(float4*)&sE[wave][half][j * 8 + 4] = *(const float4*)(er + j * 8 + 4);
        }
        __builtin_amdgcn_wave_barrier();
        float ex = sE[wave][half][head * 2];
        float pv = sE[wave][half][head * 2 + 1];
        a0 += ex * sV[wave][half][head * 3];
        a1 += ex * sV[wave][half][head * 3 + 1];
        a2 += ex * sV[wave][half][head * 3 + 2];
        a3 += pv;
        den += ex;
        __builtin_amdgcn_wave_barrier();
    }
    a0 += __shfl_xor(a0, 32, 64);
    a1 += __shfl_xor(a1, 32, 64);
    a2 += __shfl_xor(a2, 32, 64);
    a3 += __shfl_xor(a3, 32, 64);
    den += __shfl_xor(den, 32, 64);
    if (half == 0) {
        float s = (d > 0) ? 1.f / den : 0.f;
        float* ap = agg + (size_t)n * 128 + head * 4;
        ap[0] = a0 * s; ap[1] = a1 * s; ap[2] = a2 * s; ap[3] = a3 * s;
    }
}

// ---------------------------------------------------------------------------
extern "C" void kernel_launch(void* const* d_in, const int* in_sizes, int n_in,
                              void* d_out, int out_size, void* d_ws, size_t ws_size,
                              hipStream_t stream)
{
    (void)n_in; (void)out_size; (void)ws_size;
    const float* feat = (const float*)d_in[0];
    const float* edge = (const float*)d_in[1];
    const float* Wq   = (const float*)d_in[2];
    const float* bq   = (const float*)d_in[3];
    const float* Wk   = (const float*)d_in[4];
    const float* bk   = (const float*)d_in[5];
    const float* Wv   = (const float*)d_in[6];
    const float* bv   = (const float*)d_in[7];
    const float* We   = (const float*)d_in[8];
    const float* be   = (const float*)d_in[9];
    const float* Wb   = (const float*)d_in[10];
    const float* bb   = (const float*)d_in[11];
    const float* Wvv  = (const float*)d_in[12];
    const float* bvv  = (const float*)d_in[13];
    const float* Wf0  = (const float*)d_in[14];
    const float* bf0  = (const float*)d_in[15];
    const float* Wf1  = (const float*)d_in[16];
    const float* bf1  = (const float*)d_in[17];
    const float* Wm0  = (const float*)d_in[18];
    const float* bm0  = (const float*)d_in[19];
    const float* Wm1  = (const float*)d_in[20];
    const float* bm1  = (const float*)d_in[21];
    const float* g_n0 = (const float*)d_in[22];
    const float* b_n0 = (const float*)d_in[23];
    const float* g_e0 = (const float*)d_in[24];
    const float* b_e0 = (const float*)d_in[25];
    const float* g_e1 = (const float*)d_in[26];
    const float* b_e1 = (const float*)d_in[27];
    const float* g_m  = (const float*)d_in[28];
    const float* b_m  = (const float*)d_in[29];
    const float* wsc  = (const float*)d_in[30];
    const int*   src  = (const int*)d_in[31];
    const int*   dst  = (const int*)d_in[32];

    const int N = in_sizes[0] / 96;
    const int E = in_sizes[1] / 32;

    float* ws    = (float*)d_ws;
    float* qkv   = ws;                                  // N*288
    float* agg   = qkv + (size_t)N * 288;               // N*128
    float* h0    = agg + (size_t)N * 128;               // N*96 (h0, later hn)
    float* hp    = h0 + (size_t)N * 96;                 // N*96
    float* exve  = hp + (size_t)N * 96;                 // E*64
    int*   eidx  = (int*)(exve + (size_t)E * 64);       // E
    int*   cnt   = eidx + E;                            // N
    int*   offv  = cnt + N;                             // N
    int*   cur   = offv + N;                            // N
    float* tbuf  = ws;                                  // N*192, reuses qkv late
    float* hout  = (float*)d_out;
    float* eoutp = (float*)d_out + (size_t)N * 96;

    hipMemsetAsync(cnt, 0, (size_t)N * sizeof(int), stream);

    const int mt = (N + 63) / 64;
    const int et = (E + 255) / 256;

    // CSR bucketing (independent of node-side work)
    count_kernel<<<et, 256, 0, stream>>>(dst, cnt, E);
    scan_kernel<<<1, 1024, 0, stream>>>(cnt, offv, cur, N);
    scatter_kernel<<<et, 256, 0, stream>>>(dst, cur, eidx, E);

    // node side: h0 = LN(feat); qkv = h0 @ [Wq|Wk|Wv]
    ln96_kernel<<<(N + 7) / 8, 256, 0, stream>>>(feat, g_n0, b_n0, h0, N);
    gemm_kernel<0,0><<<dim3(mt, 2), 192, 0, stream>>>(h0, 96, Wq, 96, bq, nullptr, nullptr, qkv, 288, 0,   N, 96);
    gemm_kernel<0,0><<<dim3(mt, 2), 192, 0, stream>>>(h0, 96, Wk, 96, bk, nullptr, nullptr, qkv, 288, 96,  N, 96);
    gemm_kernel<0,0><<<dim3(mt, 2), 192, 0, stream>>>(h0, 96, Wv, 96, bv, nullptr, nullptr, qkv, 288, 192, N, 96);

    // edge pass (streams exve, writes e output) — no atomics
    edge_kernel<<<4096, 256, 0, stream>>>(edge, qkv, src, dst,
                                          We, be, Wb, bb, Wf0, bf0, Wf1, bf1,
                                          g_e0, b_e0, g_e1, b_e1,
                                          exve, eoutp, E);

    // gather per node -> normalized agg[N,128]
    gather_kernel<<<(N + 3) / 4, 256, 0, stream>>>(exve, qkv, src, eidx, offv, cnt, agg, N);

    // h_pre = feat*(1+w) + agg @ Wvv + bvv
    gemm_kernel<0,1><<<dim3(mt, 2), 192, 0, stream>>>(agg, 128, Wvv, 96, bvv, feat, wsc, hp, 96, 0, N, 128);
    // hn = LN(h_pre)
    ln96_kernel<<<(N + 7) / 8, 256, 0, stream>>>(hp, g_m, b_m, h0, N);
    // t = relu(hn @ Wm0 + bm0)
    gemm_kernel<1,0><<<dim3(mt, 4), 192, 0, stream>>>(h0, 96, Wm0, 192, bm0, nullptr, nullptr, tbuf, 192, 0, N, 96);
    // h_out = h_pre + t @ Wm1 + bm1
    gemm_kernel<0,1><<<dim3(mt, 2), 192, 0, stream>>>(tbuf, 192, Wm1, 96, bm1, hp, nullptr, hout, 96, 0, N, 192);
}

// Round 4
// 1739.052 us; speedup vs baseline: 3.0128x; 1.5018x over previous
//
#include <hip/hip_runtime.h>
#include <cstdint>
#include <cstddef>

// ---------------------------------------------------------------------------
// EGT layer, f32.  N nodes (DIM=96, H=32, HD=3), E edges.
// Edge pass split: score_kernel (32-lane/edge, LDS-staged q/k gather) +
// edge_bulk_kernel (edge-per-lane, register-resident matvecs, SGPR weights).
// Atomic-free aggregation via CSR bucketing.
// ---------------------------------------------------------------------------

__device__ __forceinline__ float red32(float v) {
    #pragma unroll
    for (int m = 16; m >= 1; m >>= 1) v += __shfl_xor(v, m, 64);
    return v;
}

// ---------------- row LayerNorm over D=96 ----------------
__global__ __launch_bounds__(256) void ln96_kernel(
    const float* __restrict__ x, const float* __restrict__ g,
    const float* __restrict__ b, float* __restrict__ y, int M)
{
    int lane = threadIdx.x & 31;
    int grp  = threadIdx.x >> 5;
    int r = blockIdx.x * 8 + grp;
    if (r >= M) return;
    const float* xr = x + (size_t)r * 96;
    float a0 = xr[lane], a1 = xr[lane + 32], a2 = xr[lane + 64];
    float mu = red32(a0 + a1 + a2) * (1.f / 96.f);
    float d0 = a0 - mu, d1 = a1 - mu, d2 = a2 - mu;
    float var = red32(d0 * d0 + d1 * d1 + d2 * d2) * (1.f / 96.f);
    float rs = rsqrtf(var + 1e-5f);
    float* yr = y + (size_t)r * 96;
    yr[lane]      = d0 * rs * g[lane]      + b[lane];
    yr[lane + 32] = d1 * rs * g[lane + 32] + b[lane + 32];
    yr[lane + 64] = d2 * rs * g[lane + 64] + b[lane + 64];
}

// ---------------- generic small-N GEMM: C[M,*] = A[M,K] @ B[K,*] + bias -----
template<int RELU, int RES>
__global__ __launch_bounds__(192) void gemm_kernel(
    const float* __restrict__ A, int lda,
    const float* __restrict__ B, int ldb,
    const float* __restrict__ bias,
    const float* __restrict__ resid,
    const float* __restrict__ wptr,
    float* __restrict__ C, int ldc, int n0,
    int M, int K)
{
    __shared__ float sA[32 * 68];
    __shared__ float sB[32 * 48];
    const int tid = threadIdx.x;
    const int tx = tid % 12;
    const int ty = tid / 12;
    const int m0 = blockIdx.x * 64;
    const int nb = blockIdx.y * 48;
    float acc[4][4] = {};

    for (int kc = 0; kc < K; kc += 32) {
        for (int idx = tid; idx < 64 * 32; idx += 192) {
            int m = idx >> 5, k = idx & 31;
            int row = m0 + m;
            sA[k * 68 + m] = (row < M) ? A[(size_t)row * lda + kc + k] : 0.f;
        }
        for (int idx = tid; idx < 32 * 48; idx += 192) {
            int k = idx / 48, n = idx - k * 48;
            sB[idx] = B[(size_t)(kc + k) * ldb + nb + n];
        }
        __syncthreads();
        #pragma unroll
        for (int k = 0; k < 32; k++) {
            float4 av = *(const float4*)&sA[k * 68 + ty * 4];
            float4 bv = *(const float4*)&sB[k * 48 + tx * 4];
            float a4[4] = {av.x, av.y, av.z, av.w};
            float b4[4] = {bv.x, bv.y, bv.z, bv.w};
            #pragma unroll
            for (int i = 0; i < 4; i++)
                #pragma unroll
                for (int j = 0; j < 4; j++)
                    acc[i][j] += a4[i] * b4[j];
        }
        __syncthreads();
    }

    float scale = 1.f;
    if (RES) scale = wptr ? (1.f + wptr[0]) : 1.f;
    #pragma unroll
    for (int i = 0; i < 4; i++) {
        int row = m0 + ty * 4 + i;
        if (row >= M) continue;
        #pragma unroll
        for (int j = 0; j < 4; j++) {
            int col = nb + tx * 4 + j;
            float v = acc[i][j] + bias[col];
            if (RELU) v = fmaxf(v, 0.f);
            if (RES) v += scale * resid[(size_t)row * ldc + n0 + col];
            C[(size_t)row * ldc + n0 + col] = v;
        }
    }
}

// ---------------- CSR bucketing ----------------
__global__ __launch_bounds__(256) void count_kernel(
    const int* __restrict__ dst, int* __restrict__ cnt, int E)
{
    int i = blockIdx.x * 256 + threadIdx.x;
    if (i < E) atomicAdd(&cnt[dst[i]], 1);
}

__global__ __launch_bounds__(1024) void scan_kernel(
    const int* __restrict__ cnt, int* __restrict__ off, int* __restrict__ cur, int N)
{
    __shared__ int s[1024];
    const int tid = threadIdx.x;
    const int chunk = (N + 1023) >> 10;
    const int lo = tid * chunk;
    const int hi = min(lo + chunk, N);
    int sum = 0;
    for (int i = lo; i < hi; i++) sum += cnt[i];
    s[tid] = sum;
    __syncthreads();
    for (int d = 1; d < 1024; d <<= 1) {
        int v = (tid >= d) ? s[tid - d] : 0;
        __syncthreads();
        s[tid] += v;
        __syncthreads();
    }
    int base = (tid == 0) ? 0 : s[tid - 1];
    for (int i = lo; i < hi; i++) {
        off[i] = base; cur[i] = base;
        base += cnt[i];
    }
}

__global__ __launch_bounds__(256) void scatter_kernel(
    const int* __restrict__ dst, int* __restrict__ cur,
    int* __restrict__ eidx, int E)
{
    int i = blockIdx.x * 256 + threadIdx.x;
    if (i < E) {
        int p = atomicAdd(&cur[dst[i]], 1);
        eidx[p] = i;
    }
}

// ---------------- Wf0 transpose: Wf0T[j][i] = Wf0[i][j]  (32x64 -> 64x32) ---
__global__ __launch_bounds__(1024) void transpose_wf0_kernel(
    const float* __restrict__ Wf0, float* __restrict__ Wf0T)
{
    for (int t = threadIdx.x; t < 2048; t += 1024) {
        int i = t >> 6, j = t & 63;
        Wf0T[j * 32 + i] = Wf0[t];
    }
}

// ---------------- score: qk[e][h] = 0.5 * <k[src][h], q[dst][h]> -----------
__global__ __launch_bounds__(256) void score_kernel(
    const float* __restrict__ qkv, const int* __restrict__ src,
    const int* __restrict__ dst, float* __restrict__ qk, int E)
{
    __shared__ float sQ[8][96], sK[8][96];
    const int lane = threadIdx.x & 31;
    const int grp  = threadIdx.x >> 5;
    long long e = (long long)blockIdx.x * 8 + grp;
    if (e >= E) return;
    int sn = src[e], dn = dst[e];
    if (lane < 24) {
        float4 qv = *(const float4*)(qkv + (size_t)dn * 288 + lane * 4);
        float4 kv = *(const float4*)(qkv + (size_t)sn * 288 + 96 + lane * 4);
        *(float4*)&sQ[grp][lane * 4] = qv;
        *(float4*)&sK[grp][lane * 4] = kv;
    }
    __builtin_amdgcn_wave_barrier();
    float q0 = sQ[grp][lane * 3], q1 = sQ[grp][lane * 3 + 1], q2 = sQ[grp][lane * 3 + 2];
    float k0 = sK[grp][lane * 3], k1 = sK[grp][lane * 3 + 1], k2 = sK[grp][lane * 3 + 2];
    qk[e * 32 + lane] = (k0 * q0 + k1 * q1 + k2 * q2) * 0.5f;
}

// ---------------- bulk edge pass: ONE EDGE PER LANE ----------------
// Reads edge row + qk row into registers; both LNs lane-private (no shfl);
// matvecs use wave-uniform weights (s_load -> SGPR operand FMAs).
__global__ __launch_bounds__(256) void edge_bulk_kernel(
    const float* __restrict__ edge, const float* __restrict__ qk,
    const float* __restrict__ We, const float* __restrict__ be,
    const float* __restrict__ Wb, const float* __restrict__ bb,
    const float* __restrict__ Wf0T, const float* __restrict__ bf0,
    const float* __restrict__ Wf1, const float* __restrict__ bf1,
    const float* __restrict__ ge0, const float* __restrict__ be0,
    const float* __restrict__ ge1, const float* __restrict__ be1,
    float* __restrict__ exve, float* __restrict__ eout, int E)
{
    long long e = (long long)blockIdx.x * 256 + threadIdx.x;
    if (e >= E) return;

    // ---- load edge row (8 x float4, lane-private line) ----
    float ev[32];
    const float* erow = edge + e * 32;
    #pragma unroll
    for (int j = 0; j < 8; j++) {
        float4 t = *(const float4*)(erow + j * 4);
        ev[j * 4] = t.x; ev[j * 4 + 1] = t.y; ev[j * 4 + 2] = t.z; ev[j * 4 + 3] = t.w;
    }
    // ---- LN(edge) -> ew, lane-private tree reduce ----
    float s[16];
    #pragma unroll
    for (int i = 0; i < 16; i++) s[i] = ev[i] + ev[i + 16];
    #pragma unroll
    for (int w = 8; w >= 1; w >>= 1)
        #pragma unroll
        for (int i = 0; i < 8; i++) if (i < w) s[i] += s[i + w];
    float mu = s[0] * (1.f / 32.f);
    #pragma unroll
    for (int i = 0; i < 16; i++) {
        float d0 = ev[i] - mu, d1 = ev[i + 16] - mu;
        s[i] = d0 * d0 + d1 * d1;
    }
    #pragma unroll
    for (int w = 8; w >= 1; w >>= 1)
        #pragma unroll
        for (int i = 0; i < 8; i++) if (i < w) s[i] += s[i + w];
    float rs = rsqrtf(s[0] * (1.f / 32.f) + 1e-5f);
    float ew[32];
    #pragma unroll
    for (int h = 0; h < 32; h++) ew[h] = (ev[h] - mu) * rs * ge0[h] + be0[h];

    // ---- sc = qk + bb + ew@Wb ; veh = be + ew@We  (SGPR-weight FMAs) ----
    float sc[32], veh[32];
    const float* qrow = qk + e * 32;
    #pragma unroll
    for (int j = 0; j < 8; j++) {
        float4 t = *(const float4*)(qrow + j * 4);
        sc[j * 4] = t.x; sc[j * 4 + 1] = t.y; sc[j * 4 + 2] = t.z; sc[j * 4 + 3] = t.w;
    }
    #pragma unroll
    for (int h = 0; h < 32; h++) { sc[h] += bb[h]; veh[h] = be[h]; }
    #pragma unroll
    for (int i = 0; i < 32; i++) {
        const float* wbr = Wb + i * 32;
        const float* wer = We + i * 32;
        float ei = ew[i];
        #pragma unroll
        for (int h = 0; h < 32; h++) {
            sc[h]  += ei * wbr[h];
            veh[h] += ei * wer[h];
        }
    }

    // ---- exp + stream {ex, ex*ve} (16B chunks, lane-private 256B row) ----
    float* xrow = exve + e * 64;
    #pragma unroll
    for (int h = 0; h < 32; h += 2) {
        float x0 = __expf(sc[h]), x1 = __expf(sc[h + 1]);
        float4 st; st.x = x0; st.y = x0 * veh[h]; st.z = x1; st.w = x1 * veh[h + 1];
        *(float4*)(xrow + h * 2) = st;
    }

    // ---- er = sc + edge ; LN -> en ; out = er + bf1 (FFN residual acc) ----
    float er[32];
    #pragma unroll
    for (int h = 0; h < 32; h++) er[h] = sc[h] + ev[h];
    #pragma unroll
    for (int i = 0; i < 16; i++) s[i] = er[i] + er[i + 16];
    #pragma unroll
    for (int w = 8; w >= 1; w >>= 1)
        #pragma unroll
        for (int i = 0; i < 8; i++) if (i < w) s[i] += s[i + w];
    float mu2 = s[0] * (1.f / 32.f);
    #pragma unroll
    for (int i = 0; i < 16; i++) {
        float d0 = er[i] - mu2, d1 = er[i + 16] - mu2;
        s[i] = d0 * d0 + d1 * d1;
    }
    #pragma unroll
    for (int w = 8; w >= 1; w >>= 1)
        #pragma unroll
        for (int i = 0; i < 8; i++) if (i < w) s[i] += s[i + w];
    float rs2 = rsqrtf(s[0] * (1.f / 32.f) + 1e-5f);
    float en[32], out[32];
    #pragma unroll
    for (int h = 0; h < 32; h++) {
        en[h]  = (er[h] - mu2) * rs2 * ge1[h] + be1[h];
        out[h] = er[h] + bf1[h];
    }

    // ---- FFN: runtime j-loop (small code), f_j scalar, no f array ----
    for (int j = 0; j < 64; j++) {
        const float* w0 = Wf0T + j * 32;   // contiguous (transposed)
        float f = bf0[j];
        #pragma unroll
        for (int i = 0; i < 32; i++) f += en[i] * w0[i];
        f = fmaxf(f, 0.f);
        const float* w1 = Wf1 + j * 32;    // contiguous (natural)
        #pragma unroll
        for (int h = 0; h < 32; h++) out[h] += f * w1[h];
    }

    // ---- store e output (overwrites qk row; same thread, safe) ----
    float* orow = eout + e * 32;
    #pragma unroll
    for (int j = 0; j < 8; j++) {
        float4 t; t.x = out[j * 4]; t.y = out[j * 4 + 1];
        t.z = out[j * 4 + 2]; t.w = out[j * 4 + 3];
        *(float4*)(orow + j * 4) = t;
    }
}

// ---------------- gather: one wave per node, halves process alt. edges -----
__global__ __launch_bounds__(256) void gather_kernel(
    const float* __restrict__ exve, const float* __restrict__ qkv,
    const int* __restrict__ src, const int* __restrict__ eidx,
    const int* __restrict__ off, const int* __restrict__ cnt,
    float* __restrict__ agg, int N)
{
    __shared__ float sV[4][2][96];
    __shared__ float sE[4][2][64];
    const int wave = threadIdx.x >> 6;
    const int lane = threadIdx.x & 63;
    const int head = lane & 31;
    const int half = lane >> 5;
    int n = blockIdx.x * 4 + wave;
    if (n >= N) return;
    const int o = off[n], d = cnt[n];
    float a0 = 0.f, a1 = 0.f, a2 = 0.f, a3 = 0.f, den = 0.f;
    for (int i = half; i < d; i += 2) {
        int e = eidx[o + i];
        int sn = src[e];
        const float* vr = qkv + (size_t)sn * 288 + 192;
        const float* er = exve + (size_t)e * 64;
        if (head < 24) {
            *(float4*)&sV[wave][half][head * 4] = *(const float4*)(vr + head * 4);
        } else {
            int j = head - 24;
            *(float4*)&sE[wave][half][j * 8]     = *(const float4*)(er + j * 8);
            *(float4*)&sE[wave][half][j * 8 + 4] = *(const float4*)(er + j * 8 + 4);
        }
        __builtin_amdgcn_wave_barrier();
        float ex = sE[wave][half][head * 2];
        float pv = sE[wave][half][head * 2 + 1];
        a0 += ex * sV[wave][half][head * 3];
        a1 += ex * sV[wave][half][head * 3 + 1];
        a2 += ex * sV[wave][half][head * 3 + 2];
        a3 += pv;
        den += ex;
        __builtin_amdgcn_wave_barrier();
    }
    a0 += __shfl_xor(a0, 32, 64);
    a1 += __shfl_xor(a1, 32, 64);
    a2 += __shfl_xor(a2, 32, 64);
    a3 += __shfl_xor(a3, 32, 64);
    den += __shfl_xor(den, 32, 64);
    if (half == 0) {
        float sc = (d > 0) ? 1.f / den : 0.f;
        float* ap = agg + (size_t)n * 128 + head * 4;
        ap[0] = a0 * sc; ap[1] = a1 * sc; ap[2] = a2 * sc; ap[3] = a3 * sc;
    }
}

// ---------------------------------------------------------------------------
extern "C" void kernel_launch(void* const* d_in, const int* in_sizes, int n_in,
                              void* d_out, int out_size, void* d_ws, size_t ws_size,
                              hipStream_t stream)
{
    (void)n_in; (void)out_size; (void)ws_size;
    const float* feat = (const float*)d_in[0];
    const float* edge = (const float*)d_in[1];
    const float* Wq   = (const float*)d_in[2];
    const float* bq   = (const float*)d_in[3];
    const float* Wk   = (const float*)d_in[4];
    const float* bk   = (const float*)d_in[5];
    const float* Wv   = (const float*)d_in[6];
    const float* bv   = (const float*)d_in[7];
    const float* We   = (const float*)d_in[8];
    const float* be   = (const float*)d_in[9];
    const float* Wb   = (const float*)d_in[10];
    const float* bb   = (const float*)d_in[11];
    const float* Wvv  = (const float*)d_in[12];
    const float* bvv  = (const float*)d_in[13];
    const float* Wf0  = (const float*)d_in[14];
    const float* bf0  = (const float*)d_in[15];
    const float* Wf1  = (const float*)d_in[16];
    const float* bf1  = (const float*)d_in[17];
    const float* Wm0  = (const float*)d_in[18];
    const float* bm0  = (const float*)d_in[19];
    const float* Wm1  = (const float*)d_in[20];
    const float* bm1  = (const float*)d_in[21];
    const float* g_n0 = (const float*)d_in[22];
    const float* b_n0 = (const float*)d_in[23];
    const float* g_e0 = (const float*)d_in[24];
    const float* b_e0 = (const float*)d_in[25];
    const float* g_e1 = (const float*)d_in[26];
    const float* b_e1 = (const float*)d_in[27];
    const float* g_m  = (const float*)d_in[28];
    const float* b_m  = (const float*)d_in[29];
    const float* wsc  = (const float*)d_in[30];
    const int*   src  = (const int*)d_in[31];
    const int*   dst  = (const int*)d_in[32];

    const int N = in_sizes[0] / 96;
    const int E = in_sizes[1] / 32;

    float* ws    = (float*)d_ws;
    float* qkv   = ws;                                  // N*288
    float* agg   = qkv + (size_t)N * 288;               // N*128
    float* h0    = agg + (size_t)N * 128;               // N*96 (h0, later hn)
    float* hp    = h0 + (size_t)N * 96;                 // N*96
    float* exve  = hp + (size_t)N * 96;                 // E*64
    int*   eidx  = (int*)(exve + (size_t)E * 64);       // E
    int*   cnt   = eidx + E;                            // N
    int*   offv  = cnt + N;                             // N
    int*   cur   = offv + N;                            // N
    float* wf0t  = (float*)(cur + N);                   // 2048
    float* tbuf  = ws;                                  // N*192, reuses qkv late
    float* hout  = (float*)d_out;
    float* eoutp = (float*)d_out + (size_t)N * 96;      // also hosts qk scores

    hipMemsetAsync(cnt, 0, (size_t)N * sizeof(int), stream);

    const int mt = (N + 63) / 64;
    const int et = (E + 255) / 256;

    transpose_wf0_kernel<<<1, 1024, 0, stream>>>(Wf0, wf0t);

    // CSR bucketing (independent of node-side work)
    count_kernel<<<et, 256, 0, stream>>>(dst, cnt, E);
    scan_kernel<<<1, 1024, 0, stream>>>(cnt, offv, cur, N);
    scatter_kernel<<<et, 256, 0, stream>>>(dst, cur, eidx, E);

    // node side: h0 = LN(feat); qkv = h0 @ [Wq|Wk|Wv]
    ln96_kernel<<<(N + 7) / 8, 256, 0, stream>>>(feat, g_n0, b_n0, h0, N);
    gemm_kernel<0,0><<<dim3(mt, 2), 192, 0, stream>>>(h0, 96, Wq, 96, bq, nullptr, nullptr, qkv, 288, 0,   N, 96);
    gemm_kernel<0,0><<<dim3(mt, 2), 192, 0, stream>>>(h0, 96, Wk, 96, bk, nullptr, nullptr, qkv, 288, 96,  N, 96);
    gemm_kernel<0,0><<<dim3(mt, 2), 192, 0, stream>>>(h0, 96, Wv, 96, bv, nullptr, nullptr, qkv, 288, 192, N, 96);

    // scores -> eoutp region (qk buffer); then bulk edge pass consumes it
    score_kernel<<<(E + 7) / 8, 256, 0, stream>>>(qkv, src, dst, eoutp, E);
    edge_bulk_kernel<<<et, 256, 0, stream>>>(edge, eoutp,
                                             We, be, Wb, bb, wf0t, bf0, Wf1, bf1,
                                             g_e0, b_e0, g_e1, b_e1,
                                             exve, eoutp, E);

    // gather per node -> normalized agg[N,128]
    gather_kernel<<<(N + 3) / 4, 256, 0, stream>>>(exve, qkv, src, eidx, offv, cnt, agg, N);

    // h_pre = feat*(1+w) + agg @ Wvv + bvv
    gemm_kernel<0,1><<<dim3(mt, 2), 192, 0, stream>>>(agg, 128, Wvv, 96, bvv, feat, wsc, hp, 96, 0, N, 128);
    // hn = LN(h_pre)
    ln96_kernel<<<(N + 7) / 8, 256, 0, stream>>>(hp, g_m, b_m, h0, N);
    // t = relu(hn @ Wm0 + bm0)
    gemm_kernel<1,0><<<dim3(mt, 4), 192, 0, stream>>>(h0, 96, Wm0, 192, bm0, nullptr, nullptr, tbuf, 192, 0, N, 96);
    // h_out = h_pre + t @ Wm1 + bm1
    gemm_kernel<0,1><<<dim3(mt, 2), 192, 0, stream>>>(tbuf, 192, Wm1, 96, bm1, hp, nullptr, hout, 96, 0, N, 192);
}

// Round 5
// 1696.779 us; speedup vs baseline: 3.0879x; 1.0249x over previous
//
#include <hip/hip_runtime.h>
#include <cstdint>
#include <cstddef>

// ---------------------------------------------------------------------------
// EGT layer, f32.  N nodes (DIM=96, H=32, HD=3), E edges.
// Edge pass split: score_kernel (32-lane/edge, LDS-staged q/k gather) +
// edge_bulk_kernel (edge-per-lane, register-resident matvecs, SGPR weights,
// __launch_bounds__(256,2) so the ~170-reg live set stays in VGPRs).
// Atomic-free aggregation via CSR bucketing.
// ---------------------------------------------------------------------------

__device__ __forceinline__ float red32(float v) {
    #pragma unroll
    for (int m = 16; m >= 1; m >>= 1) v += __shfl_xor(v, m, 64);
    return v;
}

// ---------------- row LayerNorm over D=96 ----------------
__global__ __launch_bounds__(256) void ln96_kernel(
    const float* __restrict__ x, const float* __restrict__ g,
    const float* __restrict__ b, float* __restrict__ y, int M)
{
    int lane = threadIdx.x & 31;
    int grp  = threadIdx.x >> 5;
    int r = blockIdx.x * 8 + grp;
    if (r >= M) return;
    const float* xr = x + (size_t)r * 96;
    float a0 = xr[lane], a1 = xr[lane + 32], a2 = xr[lane + 64];
    float mu = red32(a0 + a1 + a2) * (1.f / 96.f);
    float d0 = a0 - mu, d1 = a1 - mu, d2 = a2 - mu;
    float var = red32(d0 * d0 + d1 * d1 + d2 * d2) * (1.f / 96.f);
    float rs = rsqrtf(var + 1e-5f);
    float* yr = y + (size_t)r * 96;
    yr[lane]      = d0 * rs * g[lane]      + b[lane];
    yr[lane + 32] = d1 * rs * g[lane + 32] + b[lane + 32];
    yr[lane + 64] = d2 * rs * g[lane + 64] + b[lane + 64];
}

// ---------------- generic small-N GEMM: C[M,*] = A[M,K] @ B[K,*] + bias -----
template<int RELU, int RES>
__global__ __launch_bounds__(192) void gemm_kernel(
    const float* __restrict__ A, int lda,
    const float* __restrict__ B, int ldb,
    const float* __restrict__ bias,
    const float* __restrict__ resid,
    const float* __restrict__ wptr,
    float* __restrict__ C, int ldc, int n0,
    int M, int K)
{
    __shared__ float sA[32 * 68];
    __shared__ float sB[32 * 48];
    const int tid = threadIdx.x;
    const int tx = tid % 12;
    const int ty = tid / 12;
    const int m0 = blockIdx.x * 64;
    const int nb = blockIdx.y * 48;
    float acc[4][4] = {};

    for (int kc = 0; kc < K; kc += 32) {
        for (int idx = tid; idx < 64 * 32; idx += 192) {
            int m = idx >> 5, k = idx & 31;
            int row = m0 + m;
            sA[k * 68 + m] = (row < M) ? A[(size_t)row * lda + kc + k] : 0.f;
        }
        for (int idx = tid; idx < 32 * 48; idx += 192) {
            int k = idx / 48, n = idx - k * 48;
            sB[idx] = B[(size_t)(kc + k) * ldb + nb + n];
        }
        __syncthreads();
        #pragma unroll
        for (int k = 0; k < 32; k++) {
            float4 av = *(const float4*)&sA[k * 68 + ty * 4];
            float4 bv = *(const float4*)&sB[k * 48 + tx * 4];
            float a4[4] = {av.x, av.y, av.z, av.w};
            float b4[4] = {bv.x, bv.y, bv.z, bv.w};
            #pragma unroll
            for (int i = 0; i < 4; i++)
                #pragma unroll
                for (int j = 0; j < 4; j++)
                    acc[i][j] += a4[i] * b4[j];
        }
        __syncthreads();
    }

    float scale = 1.f;
    if (RES) scale = wptr ? (1.f + wptr[0]) : 1.f;
    #pragma unroll
    for (int i = 0; i < 4; i++) {
        int row = m0 + ty * 4 + i;
        if (row >= M) continue;
        #pragma unroll
        for (int j = 0; j < 4; j++) {
            int col = nb + tx * 4 + j;
            float v = acc[i][j] + bias[col];
            if (RELU) v = fmaxf(v, 0.f);
            if (RES) v += scale * resid[(size_t)row * ldc + n0 + col];
            C[(size_t)row * ldc + n0 + col] = v;
        }
    }
}

// ---------------- CSR bucketing ----------------
__global__ __launch_bounds__(256) void count_kernel(
    const int* __restrict__ dst, int* __restrict__ cnt, int E)
{
    int i = blockIdx.x * 256 + threadIdx.x;
    if (i < E) atomicAdd(&cnt[dst[i]], 1);
}

__global__ __launch_bounds__(1024) void scan_kernel(
    const int* __restrict__ cnt, int* __restrict__ off, int* __restrict__ cur, int N)
{
    __shared__ int s[1024];
    const int tid = threadIdx.x;
    const int chunk = (N + 1023) >> 10;
    const int lo = tid * chunk;
    const int hi = min(lo + chunk, N);
    int sum = 0;
    for (int i = lo; i < hi; i++) sum += cnt[i];
    s[tid] = sum;
    __syncthreads();
    for (int d = 1; d < 1024; d <<= 1) {
        int v = (tid >= d) ? s[tid - d] : 0;
        __syncthreads();
        s[tid] += v;
        __syncthreads();
    }
    int base = (tid == 0) ? 0 : s[tid - 1];
    for (int i = lo; i < hi; i++) {
        off[i] = base; cur[i] = base;
        base += cnt[i];
    }
}

__global__ __launch_bounds__(256) void scatter_kernel(
    const int* __restrict__ dst, int* __restrict__ cur,
    int* __restrict__ eidx, int E)
{
    int i = blockIdx.x * 256 + threadIdx.x;
    if (i < E) {
        int p = atomicAdd(&cur[dst[i]], 1);
        eidx[p] = i;
    }
}

// ---------------- Wf0 transpose: Wf0T[j][i] = Wf0[i][j]  (32x64 -> 64x32) ---
__global__ __launch_bounds__(1024) void transpose_wf0_kernel(
    const float* __restrict__ Wf0, float* __restrict__ Wf0T)
{
    for (int t = threadIdx.x; t < 2048; t += 1024) {
        int i = t >> 6, j = t & 63;
        Wf0T[j * 32 + i] = Wf0[t];
    }
}

// ---------------- score: qk[e][h] = 0.5 * <k[src][h], q[dst][h]> -----------
__global__ __launch_bounds__(256) void score_kernel(
    const float* __restrict__ qkv, const int* __restrict__ src,
    const int* __restrict__ dst, float* __restrict__ qk, int E)
{
    __shared__ float sQ[8][96], sK[8][96];
    const int lane = threadIdx.x & 31;
    const int grp  = threadIdx.x >> 5;
    long long e = (long long)blockIdx.x * 8 + grp;
    if (e >= E) return;
    int sn = src[e], dn = dst[e];
    if (lane < 24) {
        float4 qv = *(const float4*)(qkv + (size_t)dn * 288 + lane * 4);
        float4 kv = *(const float4*)(qkv + (size_t)sn * 288 + 96 + lane * 4);
        *(float4*)&sQ[grp][lane * 4] = qv;
        *(float4*)&sK[grp][lane * 4] = kv;
    }
    __builtin_amdgcn_wave_barrier();
    float q0 = sQ[grp][lane * 3], q1 = sQ[grp][lane * 3 + 1], q2 = sQ[grp][lane * 3 + 2];
    float k0 = sK[grp][lane * 3], k1 = sK[grp][lane * 3 + 1], k2 = sK[grp][lane * 3 + 2];
    qk[e * 32 + lane] = (k0 * q0 + k1 * q1 + k2 * q2) * 0.5f;
}

// ---------------- bulk edge pass: ONE EDGE PER LANE ----------------
// Reads edge row + qk row into registers; both LNs lane-private (no shfl);
// matvecs use wave-uniform weights (s_load -> SGPR operand FMAs).
// launch_bounds(256,2): VGPR cap 256 so the ~170-reg live set does NOT spill.
__global__ __launch_bounds__(256, 2) void edge_bulk_kernel(
    const float* __restrict__ edge, const float* __restrict__ qk,
    const float* __restrict__ We, const float* __restrict__ be,
    const float* __restrict__ Wb, const float* __restrict__ bb,
    const float* __restrict__ Wf0T, const float* __restrict__ bf0,
    const float* __restrict__ Wf1, const float* __restrict__ bf1,
    const float* __restrict__ ge0, const float* __restrict__ be0,
    const float* __restrict__ ge1, const float* __restrict__ be1,
    float* __restrict__ exve, float* __restrict__ eout, int E)
{
    long long e = (long long)blockIdx.x * 256 + threadIdx.x;
    if (e >= E) return;

    // ---- load edge row (8 x float4, lane-private line) ----
    float ev[32];
    const float* erow = edge + e * 32;
    #pragma unroll
    for (int j = 0; j < 8; j++) {
        float4 t = *(const float4*)(erow + j * 4);
        ev[j * 4] = t.x; ev[j * 4 + 1] = t.y; ev[j * 4 + 2] = t.z; ev[j * 4 + 3] = t.w;
    }
    // ---- LN(edge) -> ew, lane-private tree reduce ----
    float s[16];
    #pragma unroll
    for (int i = 0; i < 16; i++) s[i] = ev[i] + ev[i + 16];
    #pragma unroll
    for (int w = 8; w >= 1; w >>= 1)
        #pragma unroll
        for (int i = 0; i < 8; i++) if (i < w) s[i] += s[i + w];
    float mu = s[0] * (1.f / 32.f);
    #pragma unroll
    for (int i = 0; i < 16; i++) {
        float d0 = ev[i] - mu, d1 = ev[i + 16] - mu;
        s[i] = d0 * d0 + d1 * d1;
    }
    #pragma unroll
    for (int w = 8; w >= 1; w >>= 1)
        #pragma unroll
        for (int i = 0; i < 8; i++) if (i < w) s[i] += s[i + w];
    float rs = rsqrtf(s[0] * (1.f / 32.f) + 1e-5f);
    float ew[32];
    #pragma unroll
    for (int h = 0; h < 32; h++) ew[h] = (ev[h] - mu) * rs * ge0[h] + be0[h];

    // ---- sc = qk + bb + ew@Wb ; veh = be + ew@We  (SGPR-weight FMAs) ----
    float sc[32], veh[32];
    const float* qrow = qk + e * 32;
    #pragma unroll
    for (int j = 0; j < 8; j++) {
        float4 t = *(const float4*)(qrow + j * 4);
        sc[j * 4] = t.x; sc[j * 4 + 1] = t.y; sc[j * 4 + 2] = t.z; sc[j * 4 + 3] = t.w;
    }
    #pragma unroll
    for (int h = 0; h < 32; h++) { sc[h] += bb[h]; veh[h] = be[h]; }
    #pragma unroll
    for (int i = 0; i < 32; i++) {
        const float* wbr = Wb + i * 32;
        const float* wer = We + i * 32;
        float ei = ew[i];
        #pragma unroll
        for (int h = 0; h < 32; h++) {
            sc[h]  += ei * wbr[h];
            veh[h] += ei * wer[h];
        }
    }

    // ---- exp + stream {ex, ex*ve} (16B chunks, lane-private 256B row) ----
    float* xrow = exve + e * 64;
    #pragma unroll
    for (int h = 0; h < 32; h += 2) {
        float x0 = __expf(sc[h]), x1 = __expf(sc[h + 1]);
        float4 st; st.x = x0; st.y = x0 * veh[h]; st.z = x1; st.w = x1 * veh[h + 1];
        *(float4*)(xrow + h * 2) = st;
    }

    // ---- er = sc + edge ; LN -> en ; out = er + bf1 (FFN residual acc) ----
    float er[32];
    #pragma unroll
    for (int h = 0; h < 32; h++) er[h] = sc[h] + ev[h];
    #pragma unroll
    for (int i = 0; i < 16; i++) s[i] = er[i] + er[i + 16];
    #pragma unroll
    for (int w = 8; w >= 1; w >>= 1)
        #pragma unroll
        for (int i = 0; i < 8; i++) if (i < w) s[i] += s[i + w];
    float mu2 = s[0] * (1.f / 32.f);
    #pragma unroll
    for (int i = 0; i < 16; i++) {
        float d0 = er[i] - mu2, d1 = er[i + 16] - mu2;
        s[i] = d0 * d0 + d1 * d1;
    }
    #pragma unroll
    for (int w = 8; w >= 1; w >>= 1)
        #pragma unroll
        for (int i = 0; i < 8; i++) if (i < w) s[i] += s[i + w];
    float rs2 = rsqrtf(s[0] * (1.f / 32.f) + 1e-5f);
    float en[32], out[32];
    #pragma unroll
    for (int h = 0; h < 32; h++) {
        en[h]  = (er[h] - mu2) * rs2 * ge1[h] + be1[h];
        out[h] = er[h] + bf1[h];
    }

    // ---- FFN: runtime j-loop (small code), f_j scalar, no f array ----
    for (int j = 0; j < 64; j++) {
        const float* w0 = Wf0T + j * 32;   // contiguous (transposed)
        float f = bf0[j];
        #pragma unroll
        for (int i = 0; i < 32; i++) f += en[i] * w0[i];
        f = fmaxf(f, 0.f);
        const float* w1 = Wf1 + j * 32;    // contiguous (natural)
        #pragma unroll
        for (int h = 0; h < 32; h++) out[h] += f * w1[h];
    }

    // ---- store e output (overwrites qk row; same thread, safe) ----
    float* orow = eout + e * 32;
    #pragma unroll
    for (int j = 0; j < 8; j++) {
        float4 t; t.x = out[j * 4]; t.y = out[j * 4 + 1];
        t.z = out[j * 4 + 2]; t.w = out[j * 4 + 3];
        *(float4*)(orow + j * 4) = t;
    }
}

// ---------------- gather: one wave per node, halves process alt. edges -----
__global__ __launch_bounds__(256) void gather_kernel(
    const float* __restrict__ exve, const float* __restrict__ qkv,
    const int* __restrict__ src, const int* __restrict__ eidx,
    const int* __restrict__ off, const int* __restrict__ cnt,
    float* __restrict__ agg, int N)
{
    __shared__ float sV[4][2][96];
    __shared__ float sE[4][2][64];
    const int wave = threadIdx.x >> 6;
    const int lane = threadIdx.x & 63;
    const int head = lane & 31;
    const int half = lane >> 5;
    int n = blockIdx.x * 4 + wave;
    if (n >= N) return;
    const int o = off[n], d = cnt[n];
    float a0 = 0.f, a1 = 0.f, a2 = 0.f, a3 = 0.f, den = 0.f;
    for (int i = half; i < d; i += 2) {
        int e = eidx[o + i];
        int sn = src[e];
        const float* vr = qkv + (size_t)sn * 288 + 192;
        const float* er = exve + (size_t)e * 64;
        if (head < 24) {
            *(float4*)&sV[wave][half][head * 4] = *(const float4*)(vr + head * 4);
        } else {
            int j = head - 24;
            *(float4*)&sE[wave][half][j * 8]     = *(const float4*)(er + j * 8);
            *(float4*)&sE[wave][half][j * 8 + 4] = *(const float4*)(er + j * 8 + 4);
        }
        __builtin_amdgcn_wave_barrier();
        float ex = sE[wave][half][head * 2];
        float pv = sE[wave][half][head * 2 + 1];
        a0 += ex * sV[wave][half][head * 3];
        a1 += ex * sV[wave][half][head * 3 + 1];
        a2 += ex * sV[wave][half][head * 3 + 2];
        a3 += pv;
        den += ex;
        __builtin_amdgcn_wave_barrier();
    }
    a0 += __shfl_xor(a0, 32, 64);
    a1 += __shfl_xor(a1, 32, 64);
    a2 += __shfl_xor(a2, 32, 64);
    a3 += __shfl_xor(a3, 32, 64);
    den += __shfl_xor(den, 32, 64);
    if (half == 0) {
        float sc = (d > 0) ? 1.f / den : 0.f;
        float* ap = agg + (size_t)n * 128 + head * 4;
        ap[0] = a0 * sc; ap[1] = a1 * sc; ap[2] = a2 * sc; ap[3] = a3 * sc;
    }
}

// ---------------------------------------------------------------------------
extern "C" void kernel_launch(void* const* d_in, const int* in_sizes, int n_in,
                              void* d_out, int out_size, void* d_ws, size_t ws_size,
                              hipStream_t stream)
{
    (void)n_in; (void)out_size; (void)ws_size;
    const float* feat = (const float*)d_in[0];
    const float* edge = (const float*)d_in[1];
    const float* Wq   = (const float*)d_in[2];
    const float* bq   = (const float*)d_in[3];
    const float* Wk   = (const float*)d_in[4];
    const float* bk   = (const float*)d_in[5];
    const float* Wv   = (const float*)d_in[6];
    const float* bv   = (const float*)d_in[7];
    const float* We   = (const float*)d_in[8];
    const float* be   = (const float*)d_in[9];
    const float* Wb   = (const float*)d_in[10];
    const float* bb   = (const float*)d_in[11];
    const float* Wvv  = (const float*)d_in[12];
    const float* bvv  = (const float*)d_in[13];
    const float* Wf0  = (const float*)d_in[14];
    const float* bf0  = (const float*)d_in[15];
    const float* Wf1  = (const float*)d_in[16];
    const float* bf1  = (const float*)d_in[17];
    const float* Wm0  = (const float*)d_in[18];
    const float* bm0  = (const float*)d_in[19];
    const float* Wm1  = (const float*)d_in[20];
    const float* bm1  = (const float*)d_in[21];
    const float* g_n0 = (const float*)d_in[22];
    const float* b_n0 = (const float*)d_in[23];
    const float* g_e0 = (const float*)d_in[24];
    const float* b_e0 = (const float*)d_in[25];
    const float* g_e1 = (const float*)d_in[26];
    const float* b_e1 = (const float*)d_in[27];
    const float* g_m  = (const float*)d_in[28];
    const float* b_m  = (const float*)d_in[29];
    const float* wsc  = (const float*)d_in[30];
    const int*   src  = (const int*)d_in[31];
    const int*   dst  = (const int*)d_in[32];

    const int N = in_sizes[0] / 96;
    const int E = in_sizes[1] / 32;

    float* ws    = (float*)d_ws;
    float* qkv   = ws;                                  // N*288
    float* agg   = qkv + (size_t)N * 288;               // N*128
    float* h0    = agg + (size_t)N * 128;               // N*96 (h0, later hn)
    float* hp    = h0 + (size_t)N * 96;                 // N*96
    float* exve  = hp + (size_t)N * 96;                 // E*64
    int*   eidx  = (int*)(exve + (size_t)E * 64);       // E
    int*   cnt   = eidx + E;                            // N
    int*   offv  = cnt + N;                             // N
    int*   cur   = offv + N;                            // N
    float* wf0t  = (float*)(cur + N);                   // 2048
    float* tbuf  = ws;                                  // N*192, reuses qkv late
    float* hout  = (float*)d_out;
    float* eoutp = (float*)d_out + (size_t)N * 96;      // also hosts qk scores

    hipMemsetAsync(cnt, 0, (size_t)N * sizeof(int), stream);

    const int mt = (N + 63) / 64;
    const int et = (E + 255) / 256;

    transpose_wf0_kernel<<<1, 1024, 0, stream>>>(Wf0, wf0t);

    // CSR bucketing (independent of node-side work)
    count_kernel<<<et, 256, 0, stream>>>(dst, cnt, E);
    scan_kernel<<<1, 1024, 0, stream>>>(cnt, offv, cur, N);
    scatter_kernel<<<et, 256, 0, stream>>>(dst, cur, eidx, E);

    // node side: h0 = LN(feat); qkv = h0 @ [Wq|Wk|Wv]
    ln96_kernel<<<(N + 7) / 8, 256, 0, stream>>>(feat, g_n0, b_n0, h0, N);
    gemm_kernel<0,0><<<dim3(mt, 2), 192, 0, stream>>>(h0, 96, Wq, 96, bq, nullptr, nullptr, qkv, 288, 0,   N, 96);
    gemm_kernel<0,0><<<dim3(mt, 2), 192, 0, stream>>>(h0, 96, Wk, 96, bk, nullptr, nullptr, qkv, 288, 96,  N, 96);
    gemm_kernel<0,0><<<dim3(mt, 2), 192, 0, stream>>>(h0, 96, Wv, 96, bv, nullptr, nullptr, qkv, 288, 192, N, 96);

    // scores -> eoutp region (qk buffer); then bulk edge pass consumes it
    score_kernel<<<(E + 7) / 8, 256, 0, stream>>>(qkv, src, dst, eoutp, E);
    edge_bulk_kernel<<<et, 256, 0, stream>>>(edge, eoutp,
                                             We, be, Wb, bb, wf0t, bf0, Wf1, bf1,
                                             g_e0, b_e0, g_e1, b_e1,
                                             exve, eoutp, E);

    // gather per node -> normalized agg[N,128]
    gather_kernel<<<(N + 3) / 4, 256, 0, stream>>>(exve, qkv, src, eidx, offv, cnt, agg, N);

    // h_pre = feat*(1+w) + agg @ Wvv + bvv
    gemm_kernel<0,1><<<dim3(mt, 2), 192, 0, stream>>>(agg, 128, Wvv, 96, bvv, feat, wsc, hp, 96, 0, N, 128);
    // hn = LN(h_pre)
    ln96_kernel<<<(N + 7) / 8, 256, 0, stream>>>(hp, g_m, b_m, h0, N);
    // t = relu(hn @ Wm0 + bm0)
    gemm_kernel<1,0><<<dim3(mt, 4), 192, 0, stream>>>(h0, 96, Wm0, 192, bm0, nullptr, nullptr, tbuf, 192, 0, N, 96);
    // h_out = h_pre + t @ Wm1 + bm1
    gemm_kernel<0,1><<<dim3(mt, 2), 192, 0, stream>>>(tbuf, 192, Wm1, 96, bm1, hp, nullptr, hout, 96, 0, N, 192);
}